// Round 1
// baseline (10827.911 us; speedup 1.0000x reference)
//
#include <hip/hip_runtime.h>
#include <cstdint>

__device__ __forceinline__ float leakyf(float v){ return v > 0.f ? v : 0.01f*v; }
__device__ __forceinline__ float actf(float v, int act){
  if (act == 1) return fmaxf(v, 0.f);
  if (act == 2) return leakyf(v);
  return v;
}

// ---------------- graph build ----------------
__global__ void k_init_deg(int* deg_out, int* deg_in, int n){
  int i = blockIdx.x*blockDim.x + threadIdx.x;
  if (i < n){ deg_out[i] = 1; deg_in[i] = 1; }   // self-loop contributes 1 to each
}
__global__ void k_count(const int* __restrict__ src, const int* __restrict__ dst,
                        int* deg_out, int* deg_in, int e){
  int i = blockIdx.x*blockDim.x + threadIdx.x;
  if (i < e){ atomicAdd(&deg_out[src[i]], 1); atomicAdd(&deg_in[dst[i]], 1); }
}
__global__ void k_scan(const int* __restrict__ deg, int* rp, int n){
  __shared__ int sums[1024];
  int t = threadIdx.x;
  int per = (n + 1023)/1024;
  int base = t*per;
  int s = 0;
  for (int i = 0; i < per; ++i){ int j = base+i; if (j < n) s += deg[j]; }
  sums[t] = s; __syncthreads();
  for (int off = 1; off < 1024; off <<= 1){
    int v = 0;
    if (t >= off) v = sums[t-off];
    __syncthreads();
    if (t >= off) sums[t] += v;
    __syncthreads();
  }
  int run = (t == 0) ? 0 : sums[t-1];
  for (int i = 0; i < per; ++i){ int j = base+i; if (j < n){ rp[j] = run; run += deg[j]; } }
  if (t == 1023) rp[n] = sums[1023];
}
__global__ void k_zero_i(int* p, int n){ int i=blockIdx.x*blockDim.x+threadIdx.x; if(i<n) p[i]=0; }
__global__ void k_zero_f(float* p, int n){ int i=blockIdx.x*blockDim.x+threadIdx.x; if(i<n) p[i]=0.f; }
__global__ void k_fill(const int* __restrict__ src, const int* __restrict__ dst,
                       const int* __restrict__ rp, int* cursor, int* ci, int e, int n){
  int i = blockIdx.x*blockDim.x + threadIdx.x;
  if (i >= e + n) return;
  int s, d;
  if (i < e){ s = src[i]; d = dst[i]; } else { s = d = i - e; }
  int pos = atomicAdd(&cursor[d], 1);
  ci[rp[d] + pos] = s;
}
__global__ void k_norms(const int* deg_out, const int* deg_in, float* nsrc, float* ndst, int n){
  int i = blockIdx.x*blockDim.x + threadIdx.x;
  if (i < n){ nsrc[i] = rsqrtf((float)deg_out[i]); ndst[i] = rsqrtf((float)deg_in[i]); }
}

// ---------------- dense GEMM (f32, 128x128x16, 256 thr, 8x8/thr) ----------------
template<int ACT, bool BIAS>
__global__ __launch_bounds__(256) void k_gemm(const float* __restrict__ A, const float* __restrict__ B,
    const float* __restrict__ bias, float* __restrict__ C, int M, int Nn, int K)
{
  __shared__ float As[16][132];
  __shared__ float Bs[16][132];
  const int m0 = blockIdx.y * 128;
  const int n0 = blockIdx.x * 128;
  const int tid = threadIdx.x;
  const int tx = tid & 15, ty = tid >> 4;
  const int aj = tid & 15, ai = tid >> 4;
  const int bc = tid & 127, br = tid >> 7;
  float acc[8][8];
  #pragma unroll
  for (int i=0;i<8;++i)
    #pragma unroll
    for (int j=0;j<8;++j) acc[i][j]=0.f;

  for (int k0 = 0; k0 < K; k0 += 16){
    #pragma unroll
    for (int p = 0; p < 8; ++p){
      int m = m0 + ai + p*16;
      int kk = k0 + aj;
      As[aj][ai + p*16] = (m < M && kk < K) ? A[(size_t)m*K + kk] : 0.f;
    }
    #pragma unroll
    for (int p = 0; p < 8; ++p){
      int kk = k0 + br + p*2;
      int nn = n0 + bc;
      Bs[br + p*2][bc] = (kk < K && nn < Nn) ? B[(size_t)kk*Nn + nn] : 0.f;
    }
    __syncthreads();
    #pragma unroll
    for (int kk = 0; kk < 16; ++kk){
      float av[8], bv[8];
      #pragma unroll
      for (int i=0;i<8;++i) av[i] = As[kk][ty*8+i];
      #pragma unroll
      for (int j=0;j<8;++j) bv[j] = Bs[kk][tx*8+j];
      #pragma unroll
      for (int i=0;i<8;++i)
        #pragma unroll
        for (int j=0;j<8;++j) acc[i][j] += av[i]*bv[j];
    }
    __syncthreads();
  }
  #pragma unroll
  for (int i=0;i<8;++i){
    int m = m0 + ty*8 + i;
    if (m >= M) continue;
    #pragma unroll
    for (int j=0;j<8;++j){
      int nn = n0 + tx*8 + j;
      if (nn >= Nn) continue;
      float v = acc[i][j];
      if (BIAS) v += bias[nn];
      if (ACT==1) v = fmaxf(v,0.f);
      else if (ACT==2) v = leakyf(v);
      C[(size_t)m*Nn + nn] = v;
    }
  }
}

// ---------------- skinny GEMM: wave per row, C<=16 outputs ----------------
template<int C>
__global__ void k_skinny(const float* __restrict__ A, const float* __restrict__ B,
                         const float* __restrict__ bias, float* __restrict__ out,
                         int M, int K, int act)
{
  int row = blockIdx.x*(blockDim.x>>6) + (threadIdx.x>>6);
  int lane = threadIdx.x & 63;
  if (row >= M) return;
  const float* a = A + (size_t)row*K;
  float acc[C];
  #pragma unroll
  for (int c=0;c<C;++c) acc[c]=0.f;
  for (int k = lane; k < K; k += 64){
    float av = a[k];
    const float* b = B + (size_t)k*C;
    #pragma unroll
    for (int c=0;c<C;++c) acc[c] += av*b[c];
  }
  #pragma unroll
  for (int c=0;c<C;++c){
    #pragma unroll
    for (int off=32; off; off>>=1) acc[c] += __shfl_down(acc[c], off);
  }
  if (lane == 0){
    #pragma unroll
    for (int c=0;c<C;++c){
      float v = acc[c] + (bias ? bias[c] : 0.f);
      out[(size_t)row*C + c] = actf(v, act);
    }
  }
}

// ---------------- broad GEMM: K=10 -> wide output; block per row ----------------
__global__ void k_broad(const float* __restrict__ Z, const float* __restrict__ W,
                        const float* __restrict__ bias, float* __restrict__ out,
                        int Cc, int act)
{
  int row = blockIdx.x;
  __shared__ float zr[10];
  if (threadIdx.x < 10) zr[threadIdx.x] = Z[(size_t)row*10 + threadIdx.x];
  __syncthreads();
  for (int c = threadIdx.x; c < Cc; c += blockDim.x){
    float v = bias ? bias[c] : 0.f;
    #pragma unroll
    for (int j=0;j<10;++j) v += zr[j]*W[(size_t)j*Cc + c];
    out[(size_t)row*Cc + c] = actf(v, act);
  }
}

// ---------------- fused gate (leaky->softmax->l2) + mix, in-place capable ----------------
__global__ void k_gate_mix(const float* __restrict__ tra, const float* __restrict__ zin,
                           const float* __restrict__ w, const float* __restrict__ b,
                           float* __restrict__ mix, int W)
{
  int row = blockIdx.x;
  int tid = threadIdx.x;
  const float* tr = tra + (size_t)row*W;
  const float* zr = zin + (size_t)row*W;
  float a0=0.f, a1=0.f;
  for (int k=tid; k<W; k+=256){ float t = tr[k]; a0 += t*w[2*k];       a1 += t*w[2*k+1]; }
  for (int k=tid; k<W; k+=256){ float zv = zr[k]; a0 += zv*w[2*(W+k)]; a1 += zv*w[2*(W+k)+1]; }
  #pragma unroll
  for (int off=32; off; off>>=1){ a0 += __shfl_down(a0,off); a1 += __shfl_down(a1,off); }
  __shared__ float red0[4], red1[4], m01[2];
  int wv = tid>>6, ln = tid&63;
  if (ln==0){ red0[wv]=a0; red1[wv]=a1; }
  __syncthreads();
  if (tid==0){
    float s0 = red0[0]+red0[1]+red0[2]+red0[3] + b[0];
    float s1 = red1[0]+red1[1]+red1[2]+red1[3] + b[1];
    s0 = leakyf(s0); s1 = leakyf(s1);
    float mx = fmaxf(s0,s1);
    float e0 = expf(s0-mx), e1 = expf(s1-mx);
    // l2(softmax(e)) == e / ||e||_2
    float inv = rsqrtf(fmaxf(e0*e0+e1*e1, 1e-30f));
    m01[0] = e0*inv; m01[1] = e1*inv;
  }
  __syncthreads();
  float mz = m01[0], mt = m01[1];
  for (int k=tid; k<W; k+=256){
    float t = tr[k], zv = zr[k];
    mix[(size_t)row*W + k] = mz*zv + mt*t;
  }
}

// ---------------- SpMM gather, W-wide (W<=512), block(128) per dst row ----------------
template<int ACT>
__global__ void k_spmm_w(const float* __restrict__ h, const int* __restrict__ rp,
                         const int* __restrict__ ci, const float* __restrict__ nsrc,
                         const float* __restrict__ ndst, float* __restrict__ out, int W)
{
  int row = blockIdx.x;
  int tid = threadIdx.x;
  int e0 = rp[row], e1 = rp[row+1];
  int c0 = tid, c1 = tid+128, c2 = tid+256, c3 = tid+384;
  float acc0=0.f, acc1=0.f, acc2=0.f, acc3=0.f;
  for (int e=e0; e<e1; ++e){
    int s = ci[e];
    float ns = nsrc[s];
    const float* hr = h + (size_t)s*W;
    acc0 += ns*hr[c0];
    if (c1 < W) acc1 += ns*hr[c1];
    if (c2 < W) acc2 += ns*hr[c2];
    if (c3 < W) acc3 += ns*hr[c3];
  }
  float nd = ndst[row];
  out[(size_t)row*W + c0] = actf(acc0*nd, ACT);
  if (c1 < W) out[(size_t)row*W + c1] = actf(acc1*nd, ACT);
  if (c2 < W) out[(size_t)row*W + c2] = actf(acc2*nd, ACT);
  if (c3 < W) out[(size_t)row*W + c3] = actf(acc3*nd, ACT);
}

// ---------------- SpMM gather, width 10: thread per (row,col) ----------------
template<int ACT>
__global__ void k_spmm10(const float* __restrict__ h, const int* __restrict__ rp,
                         const int* __restrict__ ci, const float* __restrict__ nsrc,
                         const float* __restrict__ ndst, float* __restrict__ out, int n)
{
  int idx = blockIdx.x*blockDim.x + threadIdx.x;
  if (idx >= n*10) return;
  int row = idx/10, c = idx - row*10;
  int e0 = rp[row], e1 = rp[row+1];
  float acc = 0.f;
  for (int e=e0; e<e1; ++e){
    int s = ci[e];
    acc += nsrc[s]*h[(size_t)s*10 + c];
  }
  out[idx] = actf(acc*ndst[row], ACT);
}

// ---------------- u gate: concat(z1,z2,z3,z4,z) @ mlw(3020x5), leaky->softmax->l2 ----------------
__global__ void k_ugate(const float* __restrict__ z1, const float* __restrict__ z2,
                        const float* __restrict__ z3, const float* __restrict__ z4,
                        const float* __restrict__ zz, const float* __restrict__ mlw,
                        const float* __restrict__ mlb, float* __restrict__ u, int M)
{
  int row = blockIdx.x*(blockDim.x>>6) + (threadIdx.x>>6);
  int lane = threadIdx.x & 63;
  if (row >= M) return;
  float acc[5] = {0.f,0.f,0.f,0.f,0.f};
  auto proc = [&](const float* p, int off, int len){
    const float* pr = p + (size_t)row*len;
    for (int k=lane; k<len; k+=64){
      float a = pr[k];
      const float* wr = mlw + (size_t)(off+k)*5;
      #pragma unroll
      for (int c=0;c<5;++c) acc[c] += a*wr[c];
    }
  };
  proc(z1,0,500); proc(z2,500,500); proc(z3,1000,2000); proc(z4,3000,10); proc(zz,3010,10);
  #pragma unroll
  for (int c=0;c<5;++c){
    #pragma unroll
    for (int off=32; off; off>>=1) acc[c] += __shfl_down(acc[c], off);
  }
  if (lane==0){
    float v[5]; float mx = -1e30f;
    #pragma unroll
    for (int c=0;c<5;++c){ float t = leakyf(acc[c]+mlb[c]); v[c]=t; mx=fmaxf(mx,t); }
    float ss = 0.f;
    #pragma unroll
    for (int c=0;c<5;++c){ v[c] = expf(v[c]-mx); ss += v[c]*v[c]; }
    float inv = rsqrtf(fmaxf(ss, 1e-30f));
    #pragma unroll
    for (int c=0;c<5;++c) u[(size_t)row*5+c] = v[c]*inv;
  }
}

// ---------------- pre5 = (u-scaled concat) @ g5(3020x10), never materializing net ----------------
__global__ void k_pre5(const float* __restrict__ z1, const float* __restrict__ z2,
                       const float* __restrict__ z3, const float* __restrict__ z4,
                       const float* __restrict__ zz, const float* __restrict__ u,
                       const float* __restrict__ g5, float* __restrict__ out, int M)
{
  int row = blockIdx.x*(blockDim.x>>6) + (threadIdx.x>>6);
  int lane = threadIdx.x & 63;
  if (row >= M) return;
  float uv[5];
  #pragma unroll
  for (int c=0;c<5;++c) uv[c] = u[(size_t)row*5+c];
  float acc[10];
  #pragma unroll
  for (int c=0;c<10;++c) acc[c]=0.f;
  auto proc = [&](const float* p, int off, int len, float s){
    const float* pr = p + (size_t)row*len;
    for (int k=lane; k<len; k+=64){
      float a = s*pr[k];
      const float* wr = g5 + (size_t)(off+k)*10;
      #pragma unroll
      for (int c=0;c<10;++c) acc[c] += a*wr[c];
    }
  };
  proc(z1,0,500,uv[0]); proc(z2,500,500,uv[1]); proc(z3,1000,2000,uv[2]);
  proc(z4,3000,10,uv[3]); proc(zz,3010,10,uv[4]);
  #pragma unroll
  for (int c=0;c<10;++c){
    #pragma unroll
    for (int off=32; off; off>>=1) acc[c] += __shfl_down(acc[c], off);
  }
  if (lane==0){
    #pragma unroll
    for (int c=0;c<10;++c) out[(size_t)row*10+c] = acc[c];
  }
}

__global__ void k_softmax10(const float* __restrict__ h, float* __restrict__ out, int M){
  int row = blockIdx.x*blockDim.x + threadIdx.x;
  if (row >= M) return;
  float v[10]; float mx=-1e30f;
  #pragma unroll
  for (int j=0;j<10;++j){ v[j]=h[(size_t)row*10+j]; mx=fmaxf(mx,v[j]); }
  float s=0.f;
  #pragma unroll
  for (int j=0;j<10;++j){ v[j]=expf(v[j]-mx); s+=v[j]; }
  float inv=1.f/s;
  #pragma unroll
  for (int j=0;j<10;++j) out[(size_t)row*10+j]=v[j]*inv;
}

__global__ void k_q(const float* __restrict__ z, const float* __restrict__ cluster,
                    float* __restrict__ qout, float* __restrict__ colsum, int M)
{
  __shared__ float part[10];
  if (threadIdx.x < 10) part[threadIdx.x] = 0.f;
  __syncthreads();
  int row = blockIdx.x*blockDim.x + threadIdx.x;
  if (row < M){
    float zr[10];
    #pragma unroll
    for (int j=0;j<10;++j) zr[j] = z[(size_t)row*10+j];
    float qv[10]; float s=0.f;
    #pragma unroll
    for (int k=0;k<10;++k){
      float d2=0.f;
      #pragma unroll
      for (int j=0;j<10;++j){ float t = zr[j]-cluster[k*10+j]; d2 += t*t; }
      float qq = 1.f/(1.f+d2);   // V=1, exponent (V+1)/2 = 1
      qv[k]=qq; s+=qq;
    }
    float inv = 1.f/s;
    #pragma unroll
    for (int k=0;k<10;++k){
      float val = qv[k]*inv;
      qout[(size_t)row*10+k] = val;
      atomicAdd(&part[k], val);
    }
  }
  __syncthreads();
  if (threadIdx.x < 10) atomicAdd(&colsum[threadIdx.x], part[threadIdx.x]);
}

__global__ void k_p(const float* __restrict__ q, const float* __restrict__ colsum,
                    float* __restrict__ pout, int M){
  int row = blockIdx.x*blockDim.x + threadIdx.x;
  if (row >= M) return;
  float w[10]; float s=0.f;
  #pragma unroll
  for (int k=0;k<10;++k){ float qq=q[(size_t)row*10+k]; float ww=qq*qq/colsum[k]; w[k]=ww; s+=ww; }
  float inv=1.f/s;
  #pragma unroll
  for (int k=0;k<10;++k) pout[(size_t)row*10+k]=w[k]*inv;
}

extern "C" void kernel_launch(void* const* d_in, const int* in_sizes, int n_in,
                              void* d_out, int out_size, void* d_ws, size_t ws_size,
                              hipStream_t stream)
{
  const float* x   = (const float*)d_in[0];
  const float* ew1 = (const float*)d_in[1];  const float* eb1 = (const float*)d_in[2];
  const float* ew2 = (const float*)d_in[3];  const float* eb2 = (const float*)d_in[4];
  const float* ew3 = (const float*)d_in[5];  const float* eb3 = (const float*)d_in[6];
  const float* zw  = (const float*)d_in[7];  const float* zb  = (const float*)d_in[8];
  const float* dw1 = (const float*)d_in[9];  const float* db1 = (const float*)d_in[10];
  const float* dw2 = (const float*)d_in[11]; const float* db2 = (const float*)d_in[12];
  const float* dw3 = (const float*)d_in[13]; const float* db3 = (const float*)d_in[14];
  const float* xw  = (const float*)d_in[15]; const float* xb  = (const float*)d_in[16];
  const float* g1  = (const float*)d_in[17];
  const float* g2  = (const float*)d_in[18];
  const float* g3  = (const float*)d_in[19];
  const float* g4  = (const float*)d_in[20];
  const float* g5  = (const float*)d_in[21];
  const float* m1w = (const float*)d_in[22]; const float* m1b = (const float*)d_in[23];
  const float* m2w = (const float*)d_in[24]; const float* m2b = (const float*)d_in[25];
  const float* m3w = (const float*)d_in[26]; const float* m3b = (const float*)d_in[27];
  const float* mlw = (const float*)d_in[28]; const float* mlb = (const float*)d_in[29];
  const float* cluster = (const float*)d_in[30];
  const int* src = (const int*)d_in[31];
  const int* dst = (const int*)d_in[32];

  const int NI=2000, H1=500, H2=500, H3=2000, NZ=10;
  const int N = in_sizes[0] / NI;      // 20000
  const int E = in_sizes[31];          // 320000
  const int M_tot = E + N;

  float* out = (float*)d_out;
  float* out_xbar = out;                          // N*NI
  float* out_q    = out + (size_t)N*NI;           // N*NZ
  float* out_pred = out_q + (size_t)N*NZ;         // N*NZ
  float* out_p    = out_pred + (size_t)N*NZ;      // N*NZ

  // ---- workspace carve (all written before read each launch) ----
  char* base = (char*)d_ws;
  size_t off = 0;
  auto AF = [&](size_t e)->float*{ float* r=(float*)(base+off); off += ((e*sizeof(float)+15)&~(size_t)15); return r; };
  auto AI = [&](size_t e)->int*  { int*   r=(int*)  (base+off); off += ((e*sizeof(int)  +15)&~(size_t)15); return r; };

  int* deg_out = AI(N); int* deg_in = AI(N);
  int* rp = AI(N+1); int* cursor = AI(N); int* ci = AI(M_tot);
  float* nsrc = AF(N); float* ndst = AF(N); float* colsum = AF(16);
  float* tra1 = AF((size_t)N*H1);   // becomes mix1 in place
  float* tra2 = AF((size_t)N*H2);   // becomes mix2 in place
  float* tra3 = AF((size_t)N*H3);   // becomes mix3 in place
  float* zlat = AF((size_t)N*NZ);
  float* pre1 = AF((size_t)N*H1);   // x@g1, then reused as agg buffer
  float* z1   = AF((size_t)N*H1);   // during decoder: dh3 scratch
  float* z2   = AF((size_t)N*H2);   // during decoder: dh2 scratch
  float* z3   = AF((size_t)N*H3);
  float* pre4 = AF((size_t)N*NZ);
  float* z4   = AF((size_t)N*NZ);
  float* ubuf = AF((size_t)N*5);
  float* pre5 = AF((size_t)N*NZ);
  float* hbuf = AF((size_t)N*NZ);
  float* dh1  = out_xbar;           // N*H3 == N*NI: reuse x_bar output slot as dh1 scratch
  float* dh2  = z2;                 // free until GCN phase
  float* dh3  = z1;                 // free until GCN phase
  (void)ws_size; (void)out_size; (void)n_in;

  dim3 b256(256);
  // ---- graph build ----
  k_init_deg<<<(N+255)/256, b256, 0, stream>>>(deg_out, deg_in, N);
  k_count<<<(E+255)/256, b256, 0, stream>>>(src, dst, deg_out, deg_in, E);
  k_scan<<<1, 1024, 0, stream>>>(deg_in, rp, N);
  k_zero_i<<<(N+255)/256, b256, 0, stream>>>(cursor, N);
  k_zero_f<<<1, 64, 0, stream>>>(colsum, 16);
  k_fill<<<(M_tot+255)/256, b256, 0, stream>>>(src, dst, rp, cursor, ci, E, N);
  k_norms<<<(N+255)/256, b256, 0, stream>>>(deg_out, deg_in, nsrc, ndst, N);

  #define GEMM(ACT,BIAS,A,B,BP,C,MM,NN,KK) do{ \
    dim3 g(((NN)+127)/128, ((MM)+127)/128); \
    k_gemm<ACT,BIAS><<<g, b256, 0, stream>>>((A),(B),(BP),(C),(MM),(NN),(KK)); }while(0)

  // ---- encoder ----
  GEMM(1,true,  x,    ew1, eb1, tra1, N, H1, NI);
  GEMM(1,true,  tra1, ew2, eb2, tra2, N, H2, H1);
  GEMM(1,true,  tra2, ew3, eb3, tra3, N, H3, H2);
  k_skinny<10><<<(N+3)/4, b256, 0, stream>>>(tra3, zw, zb, zlat, N, H3, 0);
  // ---- decoder ----
  k_broad<<<N, b256, 0, stream>>>(zlat, dw1, db1, dh1, H3, 1);
  GEMM(1,true,  dh1, dw2, db2, dh2, N, H2, H3);
  GEMM(1,true,  dh2, dw3, db3, dh3, N, H1, H2);
  GEMM(0,true,  dh3, xw,  xb,  out_xbar, N, NI, H1);
  // ---- GCN branch ----
  GEMM(0,false, x, g1, nullptr, pre1, N, H1, NI);
  k_spmm_w<2><<<N, 128, 0, stream>>>(pre1, rp, ci, nsrc, ndst, z1, H1);        // z1 = leaky(agg)
  k_gate_mix<<<N, b256, 0, stream>>>(tra1, z1, m1w, m1b, tra1, H1);            // tra1 <- mix1
  k_spmm_w<0><<<N, 128, 0, stream>>>(tra1, rp, ci, nsrc, ndst, pre1, H1);      // agg2
  GEMM(2,false, pre1, g2, nullptr, z2, N, H2, H1);                             // z2 = leaky(agg2@g2)
  k_gate_mix<<<N, b256, 0, stream>>>(tra2, z2, m2w, m2b, tra2, H2);            // tra2 <- mix2
  k_spmm_w<0><<<N, 128, 0, stream>>>(tra2, rp, ci, nsrc, ndst, pre1, H2);      // agg3
  GEMM(2,false, pre1, g3, nullptr, z3, N, H3, H2);                             // z3 = leaky(agg3@g3)
  k_gate_mix<<<N, b256, 0, stream>>>(tra3, z3, m3w, m3b, tra3, H3);            // tra3 <- mix3
  k_skinny<10><<<(N+3)/4, b256, 0, stream>>>(tra3, g4, nullptr, pre4, N, H3, 0);
  k_spmm10<2><<<(N*10+255)/256, b256, 0, stream>>>(pre4, rp, ci, nsrc, ndst, z4, N); // z4
  k_ugate<<<(N+3)/4, b256, 0, stream>>>(z1, z2, z3, z4, zlat, mlw, mlb, ubuf, N);
  k_pre5<<<(N+3)/4, b256, 0, stream>>>(z1, z2, z3, z4, zlat, ubuf, g5, pre5, N);
  k_spmm10<0><<<(N*10+255)/256, b256, 0, stream>>>(pre5, rp, ci, nsrc, ndst, hbuf, N);
  k_softmax10<<<(N+255)/256, b256, 0, stream>>>(hbuf, out_pred, N);
  // ---- clustering head ----
  k_q<<<(N+255)/256, b256, 0, stream>>>(zlat, cluster, out_q, colsum, N);
  k_p<<<(N+255)/256, b256, 0, stream>>>(out_q, colsum, out_p, N);
  #undef GEMM
}

// Round 2
// 2232.323 us; speedup vs baseline: 4.8505x; 4.8505x over previous
//
#include <hip/hip_runtime.h>
#include <cstdint>

typedef _Float16 half8 __attribute__((ext_vector_type(8)));
typedef float f32x4 __attribute__((ext_vector_type(4)));

__device__ __forceinline__ float leakyf(float v){ return v > 0.f ? v : 0.01f*v; }
__device__ __forceinline__ float actf(float v, int act){
  if (act == 1) return fmaxf(v, 0.f);
  if (act == 2) return leakyf(v);
  return v;
}

__device__ __forceinline__ void gl_lds16(const void* g, void* l){
  __builtin_amdgcn_global_load_lds((const __attribute__((address_space(1))) void*)g,
                                   (__attribute__((address_space(3))) void*)l, 16, 0, 0);
}

// ---------------- graph build ----------------
__global__ void k_init_deg(int* deg_out, int* deg_in, int n){
  int i = blockIdx.x*blockDim.x + threadIdx.x;
  if (i < n){ deg_out[i] = 1; deg_in[i] = 1; }
}
__global__ void k_count(const int* __restrict__ src, const int* __restrict__ dst,
                        int* deg_out, int* deg_in, int e){
  int i = blockIdx.x*blockDim.x + threadIdx.x;
  if (i < e){ atomicAdd(&deg_out[src[i]], 1); atomicAdd(&deg_in[dst[i]], 1); }
}
__global__ void k_scan(const int* __restrict__ deg, int* rp, int n){
  __shared__ int sums[1024];
  int t = threadIdx.x;
  int per = (n + 1023)/1024;
  int base = t*per;
  int s = 0;
  for (int i = 0; i < per; ++i){ int j = base+i; if (j < n) s += deg[j]; }
  sums[t] = s; __syncthreads();
  for (int off = 1; off < 1024; off <<= 1){
    int v = 0;
    if (t >= off) v = sums[t-off];
    __syncthreads();
    if (t >= off) sums[t] += v;
    __syncthreads();
  }
  int run = (t == 0) ? 0 : sums[t-1];
  for (int i = 0; i < per; ++i){ int j = base+i; if (j < n){ rp[j] = run; run += deg[j]; } }
  if (t == 1023) rp[n] = sums[1023];
}
__global__ void k_zero_i(int* p, int n){ int i=blockIdx.x*blockDim.x+threadIdx.x; if(i<n) p[i]=0; }
__global__ void k_zero_f(float* p, int n){ int i=blockIdx.x*blockDim.x+threadIdx.x; if(i<n) p[i]=0.f; }
__global__ void k_fill(const int* __restrict__ src, const int* __restrict__ dst,
                       const int* __restrict__ rp, int* cursor, int* ci, int e, int n){
  int i = blockIdx.x*blockDim.x + threadIdx.x;
  if (i >= e + n) return;
  int s, d;
  if (i < e){ s = src[i]; d = dst[i]; } else { s = d = i - e; }
  int pos = atomicAdd(&cursor[d], 1);
  ci[rp[d] + pos] = s;
}
__global__ void k_norms(const int* deg_out, const int* deg_in, float* nsrc, float* ndst, int n){
  int i = blockIdx.x*blockDim.x + threadIdx.x;
  if (i < n){ nsrc[i] = rsqrtf((float)deg_out[i]); ndst[i] = rsqrtf((float)deg_in[i]); }
}

// ---------------- conversions ----------------
// f32 [M x K] -> fp16 padded [Mp x Kp], zero pad
__global__ void k_conv_a(const float* __restrict__ in, _Float16* __restrict__ out,
                         int M, int K, int Mp, int Kp){
  long idx = (long)blockIdx.x*blockDim.x + threadIdx.x;
  long total = (long)Mp*(Kp/8);
  if (idx >= total) return;
  int kp8 = Kp/8;
  int m = (int)(idx / kp8);
  int k8 = (int)(idx % kp8) * 8;
  half8 o;
  #pragma unroll
  for (int j=0;j<8;++j){
    int k = k8+j;
    o[j] = (_Float16)((m<M && k<K) ? in[(size_t)m*K + k] : 0.f);
  }
  *(half8*)&out[(size_t)m*Kp + k8] = o;
}
// f32 [K x N] -> fp16 transposed padded [Np x Kp] (out[n][k]=in[k][n]), zero pad
__global__ void k_conv_bt(const float* __restrict__ in, _Float16* __restrict__ out,
                          int K, int N, int Np, int Kp){
  __shared__ float t[32][33];
  int kb = blockIdx.x*32, nb = blockIdx.y*32;
  int tx = threadIdx.x & 31, ty = threadIdx.x >> 5;   // 256 threads: ty 0..7
  for (int r=ty; r<32; r+=8){
    int k = kb+r, n = nb+tx;
    t[r][tx] = (k<K && n<N) ? in[(size_t)k*N+n] : 0.f;
  }
  __syncthreads();
  for (int r=ty; r<32; r+=8){
    int n = nb+r, k = kb+tx;
    if (n<Np && k<Kp) out[(size_t)n*Kp+k] = (_Float16)t[tx][r];
  }
}

// ---------------- fp16 MFMA GEMM: C = act(A @ B^T + bias) ----------------
// A [Mp x Kp] fp16 row-major, BT [Np x Kp] fp16 (B transposed), C f32 [M x Nvalid],
// Ch fp16 [Mp x Np] (padded copy for next GEMM). 128x128 tile, BK=32, 4 waves.
template<int ACT, bool BIAS, bool F32OUT, bool F16OUT>
__global__ __launch_bounds__(256) void k_hgemm(
    const _Float16* __restrict__ A, const _Float16* __restrict__ BT,
    const float* __restrict__ bias, float* __restrict__ C, _Float16* __restrict__ Ch,
    int M, int Nvalid, long Np, long Kp)
{
  __shared__ __align__(16) _Float16 Asm[128*32];
  __shared__ __align__(16) _Float16 Bsm[128*32];
  const int m0 = blockIdx.y*128, n0 = blockIdx.x*128;
  const int tid = threadIdx.x;
  const int l = tid & 63, w = tid >> 6;
  const int wr = w >> 1, wc = w & 1;       // wave sub-tile: rows wr*64, cols wc*64
  const int srow = tid >> 2, sseg = tid & 3;
  f32x4 acc[4][4] = {};

  for (long k0 = 0; k0 < Kp; k0 += 32){
    #pragma unroll
    for (int i=0;i<2;++i){
      int ar = i*64 + srow;
      gl_lds16(A  + (size_t)(m0+ar)*Kp + k0 + sseg*8, (char*)Asm + i*4096 + (size_t)tid*16);
      gl_lds16(BT + (size_t)(n0+ar)*Kp + k0 + sseg*8, (char*)Bsm + i*4096 + (size_t)tid*16);
    }
    __syncthreads();
    half8 af[4], bf[4];
    #pragma unroll
    for (int mi=0;mi<4;++mi)
      af[mi] = *(const half8*)&Asm[(size_t)(wr*64 + mi*16 + (l&15))*32 + (l>>4)*8];
    #pragma unroll
    for (int nj=0;nj<4;++nj)
      bf[nj] = *(const half8*)&Bsm[(size_t)(wc*64 + nj*16 + (l&15))*32 + (l>>4)*8];
    #pragma unroll
    for (int mi=0;mi<4;++mi)
      #pragma unroll
      for (int nj=0;nj<4;++nj)
        acc[mi][nj] = __builtin_amdgcn_mfma_f32_16x16x32_f16(af[mi], bf[nj], acc[mi][nj], 0,0,0);
    __syncthreads();
  }

  const int cr = (l>>4)*4, cc = l&15;
  #pragma unroll
  for (int mi=0;mi<4;++mi){
    #pragma unroll
    for (int nj=0;nj<4;++nj){
      int cbase = n0 + wc*64 + nj*16 + cc;
      bool cvalid = cbase < Nvalid;
      #pragma unroll
      for (int q=0;q<4;++q){
        int r = m0 + wr*64 + mi*16 + cr + q;
        float v = acc[mi][nj][q];
        if (BIAS && cvalid) v += bias[cbase];
        if (ACT==1) v = fmaxf(v,0.f); else if (ACT==2) v = leakyf(v);
        if (!cvalid) v = 0.f;
        if (F32OUT){ if (r < M && cvalid) C[(size_t)r*Nvalid + cbase] = v; }
        if (F16OUT){ Ch[(size_t)r*Np + cbase] = (_Float16)(r < M ? v : 0.f); }
      }
    }
  }
}

// ---------------- skinny GEMM: wave per row, C<=16 outputs (f32) ----------------
template<int C>
__global__ void k_skinny(const float* __restrict__ A, const float* __restrict__ B,
                         const float* __restrict__ bias, float* __restrict__ out,
                         int M, int K, int act)
{
  int row = blockIdx.x*(blockDim.x>>6) + (threadIdx.x>>6);
  int lane = threadIdx.x & 63;
  if (row >= M) return;
  const float* a = A + (size_t)row*K;
  float acc[C];
  #pragma unroll
  for (int c=0;c<C;++c) acc[c]=0.f;
  for (int k = lane; k < K; k += 64){
    float av = a[k];
    const float* b = B + (size_t)k*C;
    #pragma unroll
    for (int c=0;c<C;++c) acc[c] += av*b[c];
  }
  #pragma unroll
  for (int c=0;c<C;++c){
    #pragma unroll
    for (int off=32; off; off>>=1) acc[c] += __shfl_down(acc[c], off);
  }
  if (lane == 0){
    #pragma unroll
    for (int c=0;c<C;++c){
      float v = acc[c] + (bias ? bias[c] : 0.f);
      out[(size_t)row*C + c] = actf(v, act);
    }
  }
}

// ---------------- decoder layer 1: dh1 = relu(z @ dw1 + db1) -> fp16 padded ----------------
__global__ void k_broad_f16(const float* __restrict__ Z, const float* __restrict__ W,
                            const float* __restrict__ bias, _Float16* __restrict__ out,
                            int M, int Cc, int Kp){
  int row = blockIdx.x;    // 0..Mp-1
  __shared__ float zr[10];
  if (threadIdx.x < 10 && row < M) zr[threadIdx.x] = Z[(size_t)row*10 + threadIdx.x];
  __syncthreads();
  for (int c = threadIdx.x; c < Kp; c += blockDim.x){
    float v = 0.f;
    if (row < M && c < Cc){
      v = bias[c];
      #pragma unroll
      for (int j=0;j<10;++j) v += zr[j]*W[(size_t)j*Cc + c];
      v = fmaxf(v, 0.f);
    }
    out[(size_t)row*Kp + c] = (_Float16)v;
  }
}

// ---------------- fused gate (leaky->softmax->l2) + mix, in-place capable ----------------
__global__ void k_gate_mix(const float* __restrict__ tra, const float* __restrict__ zin,
                           const float* __restrict__ w, const float* __restrict__ b,
                           float* __restrict__ mix, int W)
{
  int row = blockIdx.x;
  int tid = threadIdx.x;
  const float* tr = tra + (size_t)row*W;
  const float* zr = zin + (size_t)row*W;
  float a0=0.f, a1=0.f;
  for (int k=tid; k<W; k+=256){ float t = tr[k]; a0 += t*w[2*k];       a1 += t*w[2*k+1]; }
  for (int k=tid; k<W; k+=256){ float zv = zr[k]; a0 += zv*w[2*(W+k)]; a1 += zv*w[2*(W+k)+1]; }
  #pragma unroll
  for (int off=32; off; off>>=1){ a0 += __shfl_down(a0,off); a1 += __shfl_down(a1,off); }
  __shared__ float red0[4], red1[4], m01[2];
  int wv = tid>>6, ln = tid&63;
  if (ln==0){ red0[wv]=a0; red1[wv]=a1; }
  __syncthreads();
  if (tid==0){
    float s0 = red0[0]+red0[1]+red0[2]+red0[3] + b[0];
    float s1 = red1[0]+red1[1]+red1[2]+red1[3] + b[1];
    s0 = leakyf(s0); s1 = leakyf(s1);
    float mx = fmaxf(s0,s1);
    float e0 = expf(s0-mx), e1 = expf(s1-mx);
    float inv = rsqrtf(fmaxf(e0*e0+e1*e1, 1e-30f));
    m01[0] = e0*inv; m01[1] = e1*inv;
  }
  __syncthreads();
  float mz = m01[0], mt = m01[1];
  for (int k=tid; k<W; k+=256){
    float t = tr[k], zv = zr[k];
    mix[(size_t)row*W + k] = mz*zv + mt*t;
  }
}

// ---------------- SpMM gather, W-wide, f32 out ----------------
template<int ACT>
__global__ void k_spmm_w(const float* __restrict__ h, const int* __restrict__ rp,
                         const int* __restrict__ ci, const float* __restrict__ nsrc,
                         const float* __restrict__ ndst, float* __restrict__ out, int W)
{
  int row = blockIdx.x;
  int tid = threadIdx.x;
  int e0 = rp[row], e1 = rp[row+1];
  int c0 = tid, c1 = tid+128, c2 = tid+256, c3 = tid+384;
  float acc0=0.f, acc1=0.f, acc2=0.f, acc3=0.f;
  for (int e=e0; e<e1; ++e){
    int s = ci[e];
    float ns = nsrc[s];
    const float* hr = h + (size_t)s*W;
    acc0 += ns*hr[c0];
    if (c1 < W) acc1 += ns*hr[c1];
    if (c2 < W) acc2 += ns*hr[c2];
    if (c3 < W) acc3 += ns*hr[c3];
  }
  float nd = ndst[row];
  out[(size_t)row*W + c0] = actf(acc0*nd, ACT);
  if (c1 < W) out[(size_t)row*W + c1] = actf(acc1*nd, ACT);
  if (c2 < W) out[(size_t)row*W + c2] = actf(acc2*nd, ACT);
  if (c3 < W) out[(size_t)row*W + c3] = actf(acc3*nd, ACT);
}

// ---------------- SpMM gather, fp16 padded out (no act; raw agg) ----------------
__global__ void k_spmm_f16(const float* __restrict__ h, const int* __restrict__ rp,
                           const int* __restrict__ ci, const float* __restrict__ nsrc,
                           const float* __restrict__ ndst, _Float16* __restrict__ out,
                           int W, int Wp)
{
  int row = blockIdx.x;
  int tid = threadIdx.x;
  int e0 = rp[row], e1 = rp[row+1];
  int c0 = tid, c1 = tid+128, c2 = tid+256, c3 = tid+384;
  float acc0=0.f, acc1=0.f, acc2=0.f, acc3=0.f;
  for (int e=e0; e<e1; ++e){
    int s = ci[e];
    float ns = nsrc[s];
    const float* hr = h + (size_t)s*W;
    acc0 += ns*hr[c0];
    if (c1 < W) acc1 += ns*hr[c1];
    if (c2 < W) acc2 += ns*hr[c2];
    if (c3 < W) acc3 += ns*hr[c3];
  }
  float nd = ndst[row];
  out[(size_t)row*Wp + c0] = (_Float16)(acc0*nd);
  out[(size_t)row*Wp + c1] = (_Float16)(c1 < W ? acc1*nd : 0.f);
  out[(size_t)row*Wp + c2] = (_Float16)(c2 < W ? acc2*nd : 0.f);
  out[(size_t)row*Wp + c3] = (_Float16)(c3 < W ? acc3*nd : 0.f);
}

// ---------------- SpMM gather, width 10 ----------------
template<int ACT>
__global__ void k_spmm10(const float* __restrict__ h, const int* __restrict__ rp,
                         const int* __restrict__ ci, const float* __restrict__ nsrc,
                         const float* __restrict__ ndst, float* __restrict__ out, int n)
{
  int idx = blockIdx.x*blockDim.x + threadIdx.x;
  if (idx >= n*10) return;
  int row = idx/10, c = idx - row*10;
  int e0 = rp[row], e1 = rp[row+1];
  float acc = 0.f;
  for (int e=e0; e<e1; ++e){
    int s = ci[e];
    acc += nsrc[s]*h[(size_t)s*10 + c];
  }
  out[idx] = actf(acc*ndst[row], ACT);
}

// ---------------- u gate ----------------
__global__ void k_ugate(const float* __restrict__ z1, const float* __restrict__ z2,
                        const float* __restrict__ z3, const float* __restrict__ z4,
                        const float* __restrict__ zz, const float* __restrict__ mlw,
                        const float* __restrict__ mlb, float* __restrict__ u, int M)
{
  int row = blockIdx.x*(blockDim.x>>6) + (threadIdx.x>>6);
  int lane = threadIdx.x & 63;
  if (row >= M) return;
  float acc[5] = {0.f,0.f,0.f,0.f,0.f};
  auto proc = [&](const float* p, int off, int len){
    const float* pr = p + (size_t)row*len;
    for (int k=lane; k<len; k+=64){
      float a = pr[k];
      const float* wr = mlw + (size_t)(off+k)*5;
      #pragma unroll
      for (int c=0;c<5;++c) acc[c] += a*wr[c];
    }
  };
  proc(z1,0,500); proc(z2,500,500); proc(z3,1000,2000); proc(z4,3000,10); proc(zz,3010,10);
  #pragma unroll
  for (int c=0;c<5;++c){
    #pragma unroll
    for (int off=32; off; off>>=1) acc[c] += __shfl_down(acc[c], off);
  }
  if (lane==0){
    float v[5]; float mx = -1e30f;
    #pragma unroll
    for (int c=0;c<5;++c){ float t = leakyf(acc[c]+mlb[c]); v[c]=t; mx=fmaxf(mx,t); }
    float ss = 0.f;
    #pragma unroll
    for (int c=0;c<5;++c){ v[c] = expf(v[c]-mx); ss += v[c]*v[c]; }
    float inv = rsqrtf(fmaxf(ss, 1e-30f));
    #pragma unroll
    for (int c=0;c<5;++c) u[(size_t)row*5+c] = v[c]*inv;
  }
}

// ---------------- pre5 ----------------
__global__ void k_pre5(const float* __restrict__ z1, const float* __restrict__ z2,
                       const float* __restrict__ z3, const float* __restrict__ z4,
                       const float* __restrict__ zz, const float* __restrict__ u,
                       const float* __restrict__ g5, float* __restrict__ out, int M)
{
  int row = blockIdx.x*(blockDim.x>>6) + (threadIdx.x>>6);
  int lane = threadIdx.x & 63;
  if (row >= M) return;
  float uv[5];
  #pragma unroll
  for (int c=0;c<5;++c) uv[c] = u[(size_t)row*5+c];
  float acc[10];
  #pragma unroll
  for (int c=0;c<10;++c) acc[c]=0.f;
  auto proc = [&](const float* p, int off, int len, float s){
    const float* pr = p + (size_t)row*len;
    for (int k=lane; k<len; k+=64){
      float a = s*pr[k];
      const float* wr = g5 + (size_t)(off+k)*10;
      #pragma unroll
      for (int c=0;c<10;++c) acc[c] += a*wr[c];
    }
  };
  proc(z1,0,500,uv[0]); proc(z2,500,500,uv[1]); proc(z3,1000,2000,uv[2]);
  proc(z4,3000,10,uv[3]); proc(zz,3010,10,uv[4]);
  #pragma unroll
  for (int c=0;c<10;++c){
    #pragma unroll
    for (int off=32; off; off>>=1) acc[c] += __shfl_down(acc[c], off);
  }
  if (lane==0){
    #pragma unroll
    for (int c=0;c<10;++c) out[(size_t)row*10+c] = acc[c];
  }
}

__global__ void k_softmax10(const float* __restrict__ h, float* __restrict__ out, int M){
  int row = blockIdx.x*blockDim.x + threadIdx.x;
  if (row >= M) return;
  float v[10]; float mx=-1e30f;
  #pragma unroll
  for (int j=0;j<10;++j){ v[j]=h[(size_t)row*10+j]; mx=fmaxf(mx,v[j]); }
  float s=0.f;
  #pragma unroll
  for (int j=0;j<10;++j){ v[j]=expf(v[j]-mx); s+=v[j]; }
  float inv=1.f/s;
  #pragma unroll
  for (int j=0;j<10;++j) out[(size_t)row*10+j]=v[j]*inv;
}

__global__ void k_q(const float* __restrict__ z, const float* __restrict__ cluster,
                    float* __restrict__ qout, float* __restrict__ colsum, int M)
{
  __shared__ float part[10];
  if (threadIdx.x < 10) part[threadIdx.x] = 0.f;
  __syncthreads();
  int row = blockIdx.x*blockDim.x + threadIdx.x;
  if (row < M){
    float zr[10];
    #pragma unroll
    for (int j=0;j<10;++j) zr[j] = z[(size_t)row*10+j];
    float qv[10]; float s=0.f;
    #pragma unroll
    for (int k=0;k<10;++k){
      float d2=0.f;
      #pragma unroll
      for (int j=0;j<10;++j){ float t = zr[j]-cluster[k*10+j]; d2 += t*t; }
      float qq = 1.f/(1.f+d2);
      qv[k]=qq; s+=qq;
    }
    float inv = 1.f/s;
    #pragma unroll
    for (int k=0;k<10;++k){
      float val = qv[k]*inv;
      qout[(size_t)row*10+k] = val;
      atomicAdd(&part[k], val);
    }
  }
  __syncthreads();
  if (threadIdx.x < 10) atomicAdd(&colsum[threadIdx.x], part[threadIdx.x]);
}

__global__ void k_p(const float* __restrict__ q, const float* __restrict__ colsum,
                    float* __restrict__ pout, int M){
  int row = blockIdx.x*blockDim.x + threadIdx.x;
  if (row >= M) return;
  float w[10]; float s=0.f;
  #pragma unroll
  for (int k=0;k<10;++k){ float qq=q[(size_t)row*10+k]; float ww=qq*qq/colsum[k]; w[k]=ww; s+=ww; }
  float inv=1.f/s;
  #pragma unroll
  for (int k=0;k<10;++k) pout[(size_t)row*10+k]=w[k]*inv;
}

extern "C" void kernel_launch(void* const* d_in, const int* in_sizes, int n_in,
                              void* d_out, int out_size, void* d_ws, size_t ws_size,
                              hipStream_t stream)
{
  const float* x   = (const float*)d_in[0];
  const float* ew1 = (const float*)d_in[1];  const float* eb1 = (const float*)d_in[2];
  const float* ew2 = (const float*)d_in[3];  const float* eb2 = (const float*)d_in[4];
  const float* ew3 = (const float*)d_in[5];  const float* eb3 = (const float*)d_in[6];
  const float* zw  = (const float*)d_in[7];  const float* zb  = (const float*)d_in[8];
  const float* dw1 = (const float*)d_in[9];  const float* db1 = (const float*)d_in[10];
  const float* dw2 = (const float*)d_in[11]; const float* db2 = (const float*)d_in[12];
  const float* dw3 = (const float*)d_in[13]; const float* db3 = (const float*)d_in[14];
  const float* xw  = (const float*)d_in[15]; const float* xb  = (const float*)d_in[16];
  const float* g1  = (const float*)d_in[17];
  const float* g2  = (const float*)d_in[18];
  const float* g3  = (const float*)d_in[19];
  const float* g4  = (const float*)d_in[20];
  const float* g5  = (const float*)d_in[21];
  const float* m1w = (const float*)d_in[22]; const float* m1b = (const float*)d_in[23];
  const float* m2w = (const float*)d_in[24]; const float* m2b = (const float*)d_in[25];
  const float* m3w = (const float*)d_in[26]; const float* m3b = (const float*)d_in[27];
  const float* mlw = (const float*)d_in[28]; const float* mlb = (const float*)d_in[29];
  const float* cluster = (const float*)d_in[30];
  const int* src = (const int*)d_in[31];
  const int* dst = (const int*)d_in[32];

  const int NI=2000, H1=500, H2=500, H3=2000;
  const int N = in_sizes[0] / NI;      // 20000
  const int E = in_sizes[31];          // 320000
  const int M_tot = E + N;
  const int Mp = ((N + 127)/128)*128;  // 20096

  float* out = (float*)d_out;
  float* out_xbar = out;                          // N*NI
  float* out_q    = out + (size_t)N*NI;
  float* out_pred = out_q + (size_t)N*10;
  float* out_p    = out_pred + (size_t)N*10;

  // ---- workspace carve ----
  char* base = (char*)d_ws;
  size_t off = 0;
  auto AF = [&](size_t e)->float*{ float* r=(float*)(base+off); off += ((e*sizeof(float)+15)&~(size_t)15); return r; };
  auto AI = [&](size_t e)->int*  { int*   r=(int*)  (base+off); off += ((e*sizeof(int)  +15)&~(size_t)15); return r; };
  auto AH = [&](size_t e)->_Float16*{ _Float16* r=(_Float16*)(base+off); off += ((e*sizeof(_Float16)+15)&~(size_t)15); return r; };

  int* deg_out = AI(N); int* deg_in = AI(N);
  int* rp = AI(N+1); int* cursor = AI(N); int* ci = AI(M_tot);
  float* nsrc = AF(N); float* ndst = AF(N); float* colsum = AF(16);
  float* tra1 = AF((size_t)N*H1);   // -> mix1 in place
  float* tra2 = AF((size_t)N*H2);   // -> mix2 in place
  float* tra3 = AF((size_t)N*H3);   // -> mix3 in place
  float* zlat = AF((size_t)N*10);
  float* pre1 = AF((size_t)N*H1);
  float* z1   = AF((size_t)N*H1);
  float* z2   = AF((size_t)N*H2);
  float* z3   = out_xbar;           // N*H3 f32 lives in x_bar slot (freed before final GEMM)
  float* pre4 = AF((size_t)N*10);
  float* z4   = AF((size_t)N*10);
  float* ubuf = AF((size_t)N*5);
  float* pre5 = AF((size_t)N*10);
  float* hbuf = AF((size_t)N*10);
  // fp16 buffers
  _Float16* xh  = AH((size_t)Mp*2048);   // x_h; later dh1_h
  _Float16* Ah1 = AH((size_t)Mp*512);    // tra1_h -> agg_h -> dh3_h
  _Float16* Ah2 = AH((size_t)Mp*512);    // tra2_h -> dh2_h
  _Float16* ew1h = AH((size_t)512*2048);
  _Float16* ew2h = AH((size_t)512*512);
  _Float16* ew3h = AH((size_t)2048*512);
  _Float16* dw2h = AH((size_t)512*2048);
  _Float16* dw3h = AH((size_t)512*512);
  _Float16* xwh  = AH((size_t)2048*512);
  _Float16* g1h  = AH((size_t)512*2048);
  _Float16* g2h  = AH((size_t)512*512);
  _Float16* g3h  = AH((size_t)2048*512);
  (void)ws_size; (void)out_size; (void)n_in;

  dim3 b256(256);
  // ---- graph build ----
  k_init_deg<<<(N+255)/256, b256, 0, stream>>>(deg_out, deg_in, N);
  k_count<<<(E+255)/256, b256, 0, stream>>>(src, dst, deg_out, deg_in, E);
  k_scan<<<1, 1024, 0, stream>>>(deg_in, rp, N);
  k_zero_i<<<(N+255)/256, b256, 0, stream>>>(cursor, N);
  k_zero_f<<<1, 64, 0, stream>>>(colsum, 16);
  k_fill<<<(M_tot+255)/256, b256, 0, stream>>>(src, dst, rp, cursor, ci, E, N);
  k_norms<<<(N+255)/256, b256, 0, stream>>>(deg_out, deg_in, nsrc, ndst, N);

  // ---- conversions ----
  {
    long tot = (long)Mp*(2048/8);
    k_conv_a<<<(tot+255)/256, b256, 0, stream>>>(x, xh, N, NI, Mp, 2048);
  }
  #define CONVBT(W_, K_, N_, NP_, KP_, OUT_) \
    k_conv_bt<<<dim3((KP_)/32,(NP_)/32), b256, 0, stream>>>((W_), (OUT_), (K_), (N_), (NP_), (KP_))
  CONVBT(ew1, 2000, 500, 512, 2048, ew1h);
  CONVBT(ew2, 500, 500, 512, 512, ew2h);
  CONVBT(ew3, 500, 2000, 2048, 512, ew3h);
  CONVBT(dw2, 2000, 500, 512, 2048, dw2h);
  CONVBT(dw3, 500, 500, 512, 512, dw3h);
  CONVBT(xw,  500, 2000, 2048, 512, xwh);
  CONVBT(g1,  2000, 500, 512, 2048, g1h);
  CONVBT(g2,  500, 500, 512, 512, g2h);
  CONVBT(g3,  500, 2000, 2048, 512, g3h);
  #undef CONVBT

  const int MT = Mp/128;   // 157
  #define HGEMM(ACT,BIAS,F32O,F16O, A_,BT_,BIASP_,C_,CH_, NV_,NP_,KP_) \
    k_hgemm<ACT,BIAS,F32O,F16O><<<dim3((NP_)/128, MT), b256, 0, stream>>>( \
      (A_),(BT_),(BIASP_),(C_),(CH_), N, (NV_), (NP_), (KP_))

  // ---- encoder (fused fp16 copies for the chain) ----
  HGEMM(1,true, true, true,  xh,  ew1h, eb1, tra1, Ah1, 500, 512, 2048);  // tra1 + tra1_h
  HGEMM(1,true, true, true,  Ah1, ew2h, eb2, tra2, Ah2, 500, 512, 512);   // tra2 + tra2_h
  HGEMM(1,true, true, false, Ah2, ew3h, eb3, tra3, (_Float16*)nullptr, 2000, 2048, 512); // tra3
  k_skinny<10><<<(N+3)/4, b256, 0, stream>>>(tra3, zw, zb, zlat, N, H3, 0);

  // ---- GCN branch ----
  HGEMM(0,false,true, false, xh,  g1h, nullptr, pre1, (_Float16*)nullptr, 500, 512, 2048); // x@g1
  k_spmm_w<2><<<N, 128, 0, stream>>>(pre1, rp, ci, nsrc, ndst, z1, H1);          // z1
  k_gate_mix<<<N, b256, 0, stream>>>(tra1, z1, m1w, m1b, tra1, H1);              // mix1
  k_spmm_f16<<<N, 128, 0, stream>>>(tra1, rp, ci, nsrc, ndst, Ah1, H1, 512);     // agg2 (fp16)
  HGEMM(2,false,true, false, Ah1, g2h, nullptr, z2, (_Float16*)nullptr, 500, 512, 512);   // z2
  k_gate_mix<<<N, b256, 0, stream>>>(tra2, z2, m2w, m2b, tra2, H2);              // mix2
  k_spmm_f16<<<N, 128, 0, stream>>>(tra2, rp, ci, nsrc, ndst, Ah1, H2, 512);     // agg3 (fp16)
  HGEMM(2,false,true, false, Ah1, g3h, nullptr, z3, (_Float16*)nullptr, 2000, 2048, 512); // z3
  k_gate_mix<<<N, b256, 0, stream>>>(tra3, z3, m3w, m3b, tra3, H3);              // mix3
  k_skinny<10><<<(N+3)/4, b256, 0, stream>>>(tra3, g4, nullptr, pre4, N, H3, 0);
  k_spmm10<2><<<(N*10+255)/256, b256, 0, stream>>>(pre4, rp, ci, nsrc, ndst, z4, N);
  k_ugate<<<(N+3)/4, b256, 0, stream>>>(z1, z2, z3, z4, zlat, mlw, mlb, ubuf, N);
  k_pre5<<<(N+3)/4, b256, 0, stream>>>(z1, z2, z3, z4, zlat, ubuf, g5, pre5, N);
  k_spmm10<0><<<(N*10+255)/256, b256, 0, stream>>>(pre5, rp, ci, nsrc, ndst, hbuf, N);
  k_softmax10<<<(N+255)/256, b256, 0, stream>>>(hbuf, out_pred, N);
  // ---- clustering head ----
  k_q<<<(N+255)/256, b256, 0, stream>>>(zlat, cluster, out_q, colsum, N);
  k_p<<<(N+255)/256, b256, 0, stream>>>(out_q, colsum, out_p, N);

  // ---- decoder (after z3/out_xbar slot is free) ----
  k_broad_f16<<<Mp, b256, 0, stream>>>(zlat, dw1, db1, xh, N, H3, 2048);         // dh1_h (reuse xh)
  HGEMM(1,true, false,true,  xh,  dw2h, db2, (float*)nullptr, Ah2, 500, 512, 2048); // dh2_h
  HGEMM(1,true, false,true,  Ah2, dw3h, db3, (float*)nullptr, Ah1, 500, 512, 512);  // dh3_h
  HGEMM(0,true, true, false, Ah1, xwh,  xb,  out_xbar, (_Float16*)nullptr, 2000, 2048, 512); // x_bar
  #undef HGEMM
}